// Round 8
// baseline (487.036 us; speedup 1.0000x reference)
//
#include <hip/hip_runtime.h>
#include <hip/hip_bf16.h>

#define T_TOK 8192
#define HDIM 1024
#define FDIM 2048
#define NEXP 8
#define NASSIGN (T_TOK * 2)
#define ROWCAP (NASSIGN + 256)  // packed rows + tail-tile slack
#define NHB 256                 // router/hist blocks (32 tokens each)
#define MAXT2 72                // max 256-row M-tiles: 16384/256 + 8

typedef __bf16 bf16;
typedef __bf16 bf16x4 __attribute__((ext_vector_type(4)));
typedef __bf16 bf16x8 __attribute__((ext_vector_type(8)));
typedef float f32x4 __attribute__((ext_vector_type(4)));

// async global->LDS, 16B per lane; LDS dest = wave-uniform base + lane*16,
// global SOURCE is per-lane (enables gather-staging).
__device__ __forceinline__ void gload_lds16(const void* g, void* l) {
    __builtin_amdgcn_global_load_lds(
        (const __attribute__((address_space(1))) void*)(uintptr_t)g,
        (__attribute__((address_space(3))) void*)(uintptr_t)l,
        16, 0, 0);
}

// ---------------- zero-fill (replaces hipMemsetAsync: graph-capture-safe) ----------------
__global__ __launch_bounds__(256) void zero_kernel(float4* __restrict__ p) {
    p[(size_t)blockIdx.x * 256 + threadIdx.x] = float4{0.f, 0.f, 0.f, 0.f};
}

// ---------------- merged transpose + fp32->bf16 for BOTH weights, one launch.
// LDS column XOR-swizzle (col ^= (row>>3)<<2, float4-aligned) breaks the old
// 8-way read conflict (68*8 = 544 = 0 mod 32): now spread across 8 banks. ----------------
__global__ __launch_bounds__(256) void transpose_both_bf16(
    const float* __restrict__ w1, bf16* __restrict__ w1t,
    const float* __restrict__ w2, bf16* __restrict__ w2t) {
    __shared__ float tile[64][68];
    int e = blockIdx.z;
    int bx = blockIdx.x;
    const float* inp;
    bf16* outp;
    int R, C, c0, r0;
    if (bx < 512) {  // w1: [H][F] -> [F][H]
        R = HDIM;
        C = FDIM;
        inp = w1 + (size_t)e * R * C;
        outp = w1t + (size_t)e * R * C;
        c0 = (bx & 31) * 64;
        r0 = (bx >> 5) * 64;
    } else {  // w2: [F][H] -> [H][F]
        int b = bx - 512;
        R = FDIM;
        C = HDIM;
        inp = w2 + (size_t)e * R * C;
        outp = w2t + (size_t)e * R * C;
        c0 = (b & 15) * 64;
        r0 = (b >> 4) * 64;
    }
    int tid = threadIdx.x;
    int tx = tid & 15, ty = tid >> 4;
#pragma unroll
    for (int i = 0; i < 4; i++) {
        int row = ty + i * 16;
        float4 v = *(const float4*)&inp[(size_t)(r0 + row) * C + c0 + tx * 4];
        *(float4*)&tile[row][(tx * 4) ^ ((row >> 3) << 2)] = v;
    }
    __syncthreads();
#pragma unroll
    for (int i = 0; i < 2; i++) {
        int idx = tid + i * 256;
        int c = idx >> 3, seg = idx & 7;
        bf16x8 v;
#pragma unroll
        for (int j = 0; j < 8; j++)
            v[j] = (bf16)tile[seg * 8 + j][c ^ (seg << 2)];
        *(bf16x8*)&outp[(size_t)(c0 + c) * R + r0 + seg * 8] = v;
    }
}

// ---------------- router: top-2 + gates + fused x->bf16 copy + fused per-block hist ------
__global__ __launch_bounds__(256) void router_kernel(
    const float* __restrict__ x, const float* __restrict__ rw,
    const float* __restrict__ rb, int* __restrict__ expert_pair,
    float2* __restrict__ gate_pair, bf16* __restrict__ xb,
    int* __restrict__ hist) {
    __shared__ float rwT[NEXP][HDIM];
    __shared__ float rbs[NEXP];
    __shared__ int sh_pair[32];
    int tid = threadIdx.x;
    for (int i = tid; i < HDIM * NEXP / 4; i += 256) {
        float4 v = ((const float4*)rw)[i];
        int h = i >> 1, e0 = (i & 1) * 4;
        rwT[e0 + 0][h] = v.x;
        rwT[e0 + 1][h] = v.y;
        rwT[e0 + 2][h] = v.z;
        rwT[e0 + 3][h] = v.w;
    }
    if (tid < NEXP) rbs[tid] = rb[tid];
    __syncthreads();
    int wave = tid >> 6, lane = tid & 63;
    int tbase = blockIdx.x * 32 + wave * 8;

    for (int tk = 0; tk < 8; tk++) {
        int t = tbase + tk;
        const float4* xt = (const float4*)(x + (size_t)t * HDIM);
        float p[NEXP];
#pragma unroll
        for (int e = 0; e < NEXP; e++) p[e] = 0.f;
#pragma unroll
        for (int it = 0; it < 4; it++) {
            float4 v = xt[it * 64 + lane];
            // fused fp32 -> bf16 copy (unpermuted); GEMM1 gathers from xb
            bf16x4 bv = {(bf16)v.x, (bf16)v.y, (bf16)v.z, (bf16)v.w};
            *(bf16x4*)&xb[(size_t)t * HDIM + (it * 64 + lane) * 4] = bv;
            int h = (it * 64 + lane) * 4;
#pragma unroll
            for (int e = 0; e < NEXP; e++) {
                float4 wv = *(const float4*)&rwT[e][h];
                p[e] += v.x * wv.x + v.y * wv.y + v.z * wv.z + v.w * wv.w;
            }
        }
#pragma unroll
        for (int off = 32; off >= 1; off >>= 1) {
#pragma unroll
            for (int e = 0; e < NEXP; e++) p[e] += __shfl_xor(p[e], off, 64);
        }
        if (lane == 0) {
            float lg[NEXP];
#pragma unroll
            for (int e = 0; e < NEXP; e++) lg[e] = p[e] + rbs[e];
            int e0 = 0;
#pragma unroll
            for (int e = 1; e < NEXP; e++)
                if (lg[e] > lg[e0]) e0 = e;
            int e1 = -1;
#pragma unroll
            for (int e = 0; e < NEXP; e++) {
                if (e == e0) continue;
                if (e1 < 0 || lg[e] > lg[e1]) e1 = e;
            }
            float z = expf(lg[e1] - lg[e0]);
            int pair = e0 | (e1 << 16);
            expert_pair[t] = pair;
            sh_pair[wave * 8 + tk] = pair;
            gate_pair[t] = make_float2(1.f / (1.f + z), z / (1.f + z));
        }
    }
    __syncthreads();
    // fused per-block histogram: 64 assignments, one wave
    if (wave == 0) {
        int tl = lane >> 1, j = lane & 1;
        int e = (sh_pair[tl] >> (16 * j)) & 0xffff;
#pragma unroll
        for (int ee = 0; ee < NEXP; ee++) {
            unsigned long long m = __ballot(e == ee);
            if (lane == ee) hist[blockIdx.x * NEXP + ee] = __popcll(m);
        }
    }
}

// ---------------- scan -> cnt, offs, per-router-block starts, 256-row tile table --------
__global__ __launch_bounds__(256) void scan_kernel(
    const int* __restrict__ hist, int* __restrict__ start,
    int* __restrict__ cnt, int* __restrict__ offs,
    int* __restrict__ tile_e2, int* __restrict__ tile_m2,
    int* __restrict__ ntiles2) {
    __shared__ int h[NHB * NEXP];
    __shared__ int tot[NEXP];
    __shared__ int offsh[NEXP];
    int tid = threadIdx.x;
    for (int i = tid; i < NHB * NEXP; i += 256) h[i] = hist[i];
    __syncthreads();
    if (tid < NEXP) {
        int s = 0;
        for (int b = 0; b < NHB; b++) s += h[b * NEXP + tid];
        tot[tid] = s;
        cnt[tid] = s;
    }
    __syncthreads();
    if (tid == 0) {
        int o = 0;
        for (int e = 0; e < NEXP; e++) {
            offsh[e] = o;
            offs[e] = o;
            o += tot[e];
        }
        int idx2 = 0;
        for (int e = 0; e < NEXP; e++) {
            int nt = (tot[e] + 255) >> 8;
            for (int m = 0; m < nt; m++) {
                tile_e2[idx2] = e;
                tile_m2[idx2] = m;
                idx2++;
            }
        }
        ntiles2[0] = idx2;
    }
    __syncthreads();
    if (tid < NEXP) {
        int run = offsh[tid];
        for (int b = 0; b < NHB; b++) {
            start[b * NEXP + tid] = run;
            run += h[b * NEXP + tid];
        }
    }
}

// ---------------- scatter: one wave per router-block (64 assignments) -------------------
__global__ __launch_bounds__(64) void scatter_kernel(
    const int* __restrict__ expert_pair, const float2* __restrict__ gate_pair,
    const int* __restrict__ start, int* __restrict__ perm,
    float* __restrict__ gatebuf) {
    int lane = threadIdx.x;
    int a = blockIdx.x * 64 + lane;
    int t = a >> 1, j = a & 1;
    int e = (expert_pair[t] >> (16 * j)) & 0xffff;
    float2 gp = gate_pair[t];
    float g = j ? gp.y : gp.x;
    int rank = 0;
    unsigned long long below = (1ull << lane) - 1ull;
#pragma unroll
    for (int ee = 0; ee < NEXP; ee++) {
        unsigned long long m = __ballot(e == ee);
        if (ee == e) rank = __popcll(m & below);
    }
    int pos = start[blockIdx.x * NEXP + e] + rank;
    perm[pos] = t;
    gatebuf[pos] = g;
}

// ================= grouped GEMM (R4/R6 geometry): BM=256 x BN=128, BK=32, 8 waves ======
// Tri-buffer LDS (72 KB -> 2 blocks/CU), counted vmcnt 6/3/0, pre-swizzled source +
// swizzled ds_read (0 conflicts, verified). GATHER (GEMM1): A rows via perm[] from
// unpermuted xb (per-lane gload source). ATOMIC (GEMM2): epilogue scatters gated
// fp32 atomicAdd directly into out[token] -> combine kernel + eout eliminated.
// Exactness: each out[t][n] receives exactly 2 adds; IEEE a+b is commutative, so
// the result is bitwise-deterministic regardless of block order.
template <bool RELU, bool GATE, bool GATHER, bool ATOMIC, int K, int N>
__global__ __launch_bounds__(512, 4) void moe_gemm_p(
    const bf16* __restrict__ A, const bf16* __restrict__ B,
    const float* __restrict__ bias, const float* __restrict__ gates,
    bf16* __restrict__ out, float* __restrict__ fout,
    const int* __restrict__ cnt, const int* __restrict__ offs,
    const int* __restrict__ tile_e2, const int* __restrict__ tile_m2,
    const int* __restrict__ ntiles2, const int* __restrict__ perm) {
    constexpr int NT = N / 128;
    constexpr int nk = K / 32;
    int ntl = ntiles2[0];
    int nact = ntl * NT;
    int f = blockIdx.x;
    if (f >= nact) return;
    // bijective chunked XCD swizzle over the active range (m204)
    int q8 = nact >> 3, r8 = nact & 7;
    int xcd = f & 7, rest = f >> 3;
    int wg = (xcd < r8) ? (xcd * (q8 + 1) + rest)
                        : (r8 * (q8 + 1) + (xcd - r8) * q8 + rest);
    int tile = wg / NT, ncol = wg - tile * NT;
    int e = tile_e2[tile];
    int n_cnt = cnt[e];
    int off_e = offs[e];
    int m0 = tile_m2[tile] * 256;
    int n0 = ncol * 128;

    __shared__ bf16 As[3][256][32];  // 48 KB
    __shared__ bf16 Bs[3][128][32];  // 24 KB

    int tid = threadIdx.x;
    int lane = tid & 63;
    int wave = tid >> 6;   // 0..7
    int wm = wave & 1;     // A rows wm*128..+127
    int wn = wave >> 1;    // B rows wn*32..+31
    int quad = lane >> 4, l16 = lane & 15;
    int rsw = (quad ^ ((l16 >> 1) & 3)) * 8;  // swizzled 16B seg (elems)

    const bf16* Be = B + (size_t)e * (size_t)N * K;

    // staging: chunk c covers LDS row c>>2 (64B rows), seg c&3; source column
    // pre-swizzled by (row>>1)&3 == (tid>>3)&3 for all our row bases.
    int r0s = tid >> 2;  // 0..127
    int segs = (tid & 3) ^ ((tid >> 3) & 3);
    const bf16* agA0;
    const bf16* agA1;
    if (GATHER) {
        int g0 = off_e + m0 + r0s;
        int g1 = off_e + m0 + 128 + r0s;
        g0 = g0 < NASSIGN ? g0 : NASSIGN - 1;
        g1 = g1 < NASSIGN ? g1 : NASSIGN - 1;
        agA0 = A + (size_t)perm[g0] * K + segs * 8;
        agA1 = A + (size_t)perm[g1] * K + segs * 8;
    } else {
        const bf16* Ae = A + (size_t)off_e * K;
        agA0 = Ae + (size_t)(m0 + r0s) * K + segs * 8;
        agA1 = Ae + (size_t)(m0 + 128 + r0s) * K + segs * 8;
    }
    const bf16* bgB0 = Be + (size_t)(n0 + r0s) * K + segs * 8;

    auto STG = [&](int buf, int kt) {
        bf16* Ab = (bf16*)As + (size_t)buf * (256 * 32);
        bf16* Bb = (bf16*)Bs + (size_t)buf * (128 * 32);
        gload_lds16(agA0 + (size_t)kt * 32, Ab + (wave * 64) * 8);
        gload_lds16(agA1 + (size_t)kt * 32, Ab + (512 + wave * 64) * 8);
        gload_lds16(bgB0 + (size_t)kt * 32, Bb + (wave * 64) * 8);
    };

    f32x4 acc[8][2];
#pragma unroll
    for (int i = 0; i < 8; i++)
#pragma unroll
        for (int j = 0; j < 2; j++) acc[i][j] = f32x4{0.f, 0.f, 0.f, 0.f};

    // prologue: stage tiles 0,1 (3 loads each)
    STG(0, 0);
    STG(1, 1);

    int b = 0, bs = 2;  // compute buf, stage buf (t+2)%3
    for (int t = 0; t < nk; t++) {
        if (t + 2 < nk) {
            STG(bs, t + 2);
            asm volatile("s_waitcnt vmcnt(6)" ::: "memory");  // tile t landed
        } else if (t + 2 == nk) {
            asm volatile("s_waitcnt vmcnt(3)" ::: "memory");
        } else {
            asm volatile("s_waitcnt vmcnt(0)" ::: "memory");
        }
        asm volatile("s_barrier" ::: "memory");

        const bf16* Ab = (const bf16*)As + (size_t)b * (256 * 32);
        const bf16* Bb = (const bf16*)Bs + (size_t)b * (128 * 32);
        bf16x8 bf0 = *(const bf16x8*)(Bb + (wn * 32 + 0 * 16 + l16) * 32 + rsw);
        bf16x8 bf1 = *(const bf16x8*)(Bb + (wn * 32 + 1 * 16 + l16) * 32 + rsw);
        bf16x8 af[4];
#pragma unroll
        for (int mi = 0; mi < 4; mi++)
            af[mi] = *(const bf16x8*)(Ab + (wm * 128 + mi * 16 + l16) * 32 + rsw);
        asm volatile("s_waitcnt lgkmcnt(0)" ::: "memory");
        __builtin_amdgcn_s_setprio(1);
#pragma unroll
        for (int mi = 0; mi < 4; mi++) {
            acc[mi][0] = __builtin_amdgcn_mfma_f32_16x16x32_bf16(af[mi], bf0, acc[mi][0], 0, 0, 0);
            acc[mi][1] = __builtin_amdgcn_mfma_f32_16x16x32_bf16(af[mi], bf1, acc[mi][1], 0, 0, 0);
        }
        __builtin_amdgcn_s_setprio(0);
#pragma unroll
        for (int mi = 0; mi < 4; mi++)
            af[mi] = *(const bf16x8*)(Ab + (wm * 128 + (4 + mi) * 16 + l16) * 32 + rsw);
        asm volatile("s_waitcnt lgkmcnt(0)" ::: "memory");
        __builtin_amdgcn_s_setprio(1);
#pragma unroll
        for (int mi = 0; mi < 4; mi++) {
            acc[4 + mi][0] = __builtin_amdgcn_mfma_f32_16x16x32_bf16(af[mi], bf0, acc[4 + mi][0], 0, 0, 0);
            acc[4 + mi][1] = __builtin_amdgcn_mfma_f32_16x16x32_bf16(af[mi], bf1, acc[4 + mi][1], 0, 0, 0);
        }
        __builtin_amdgcn_s_setprio(0);
        asm volatile("s_barrier" ::: "memory");

        b = (b == 2) ? 0 : b + 1;
        bs = (bs == 2) ? 0 : bs + 1;
    }

#pragma unroll
    for (int mi = 0; mi < 8; mi++)
#pragma unroll
        for (int r = 0; r < 4; r++) {
            int m = m0 + wm * 128 + mi * 16 + quad * 4 + r;
            if (m < n_cnt) {
                if (ATOMIC) {
                    int tok = perm[off_e + m];
                    float g = gates[off_e + m];
#pragma unroll
                    for (int nj = 0; nj < 2; nj++) {
                        int n = n0 + wn * 32 + nj * 16 + l16;
                        float v = (acc[mi][nj][r] + bias[e * N + n]) * g;
                        atomicAdd(&fout[(size_t)tok * N + n], v);
                    }
                } else {
#pragma unroll
                    for (int nj = 0; nj < 2; nj++) {
                        int n = n0 + wn * 32 + nj * 16 + l16;
                        float v = acc[mi][nj][r] + bias[e * N + n];
                        if (RELU) v = v > 0.f ? v : 0.f;
                        if (GATE) v *= gates[off_e + m];
                        out[(size_t)(off_e + m) * N + n] = (bf16)v;
                    }
                }
            }
        }
}

extern "C" void kernel_launch(void* const* d_in, const int* in_sizes, int n_in,
                              void* d_out, int out_size, void* d_ws, size_t ws_size,
                              hipStream_t stream) {
    const float* x = (const float*)d_in[0];
    const float* rw = (const float*)d_in[1];
    const float* rb = (const float*)d_in[2];
    const float* w1 = (const float*)d_in[3];
    const float* b1 = (const float*)d_in[4];
    const float* w2 = (const float*)d_in[5];
    const float* b2 = (const float*)d_in[6];
    float* out = (float*)d_out;

    char* ws = (char*)d_ws;
    size_t o = 0;
    auto alloc = [&](size_t bytes) {
        char* p = ws + o;
        o += (bytes + 255) & ~(size_t)255;
        return p;
    };
    bf16* w1t = (bf16*)alloc((size_t)NEXP * FDIM * HDIM * 2);
    bf16* w2t = (bf16*)alloc((size_t)NEXP * HDIM * FDIM * 2);
    bf16* hbuf = (bf16*)alloc((size_t)ROWCAP * FDIM * 2);
    bf16* xb = (bf16*)alloc((size_t)T_TOK * HDIM * 2);  // unpermuted bf16 x
    int* expert_pair = (int*)alloc((size_t)T_TOK * 4);
    float2* gate_pair = (float2*)alloc((size_t)T_TOK * 8);
    int* hist = (int*)alloc((size_t)NHB * NEXP * 4);
    int* start = (int*)alloc((size_t)NHB * NEXP * 4);
    int* perm = (int*)alloc((size_t)NASSIGN * 4);
    float* gatebuf = (float*)alloc((size_t)NASSIGN * 4);
    int* cnt = (int*)alloc(256);
    int* offs = (int*)alloc(256);
    int* tile_e2 = (int*)alloc((size_t)MAXT2 * 4);
    int* tile_m2 = (int*)alloc((size_t)MAXT2 * 4);
    int* ntiles2 = (int*)alloc(256);

    // out is accumulated into by GEMM2's atomic epilogue -> zero it first
    // (device kernel, not hipMemsetAsync: graph-capture-safe)
    zero_kernel<<<T_TOK * HDIM / 4 / 256, 256, 0, stream>>>((float4*)out);

    transpose_both_bf16<<<dim3(1024, 1, NEXP), 256, 0, stream>>>(w1, w1t, w2, w2t);
    router_kernel<<<NHB, 256, 0, stream>>>(x, rw, rb, expert_pair, gate_pair, xb, hist);
    scan_kernel<<<1, 256, 0, stream>>>(hist, start, cnt, offs, tile_e2, tile_m2, ntiles2);
    scatter_kernel<<<NHB, 64, 0, stream>>>(expert_pair, gate_pair, start, perm, gatebuf);
    moe_gemm_p<true, false, true, false, HDIM, FDIM>
        <<<dim3(MAXT2 * (FDIM / 128)), 512, 0, stream>>>(
            xb, w1t, b1, nullptr, hbuf, nullptr, cnt, offs, tile_e2, tile_m2,
            ntiles2, perm);
    moe_gemm_p<false, true, false, true, FDIM, HDIM>
        <<<dim3(MAXT2 * (HDIM / 128)), 512, 0, stream>>>(
            hbuf, w2t, b2, gatebuf, nullptr, out, cnt, offs, tile_e2, tile_m2,
            ntiles2, perm);
}